// Round 5
// baseline (196.313 us; speedup 1.0000x reference)
//
#include <hip/hip_runtime.h>

#define D_ 160
#define H_ 192
#define W_ 160
#define HW_ (H_*W_)
#define V_ (D_*H_*W_)
#define NTOT (2*V_)

#define TW 32
#define TH 16
#define DC 20
#define NCHUNK (D_/DC)    // 8
#define RH 24             // TH + 8 halo
#define RWP 41            // 40 cols + 1 pad
#define TWP 33            // 32 cols + 1 pad
#define NSTEP (DC+10)     // 30
#define NBLOCKS (5*12*NCHUNK*2)   // 960

// RTNE f32x2 -> packed bf16x2 (p0 high, p1 low) and back.
__device__ inline unsigned pack_bf2(float a, float b) {
  unsigned ua = __float_as_uint(a), ub = __float_as_uint(b);
  ua += 0x7fffu + ((ua >> 16) & 1u);
  ub += 0x7fffu + ((ub >> 16) & 1u);
  return (ua & 0xffff0000u) | (ub >> 16);
}
__device__ inline float2 unpack_bf2(unsigned u) {
  return make_float2(__uint_as_float(u & 0xffff0000u),
                     __uint_as_float(u << 16));
}

// ---------------------------------------------------------------------------
// Fused separable 9x9x9 box filter + NCC.
// Two barriers/step, single ws buffer (31.6 KB total LDS -> 5 blocks/CU):
//   A: global->reg loads for slice s=c0-4+t
//   C: H-dir 9-sums of slice t-2 from ws + D-ring (bf16-packed, static slot)
//   sync1
//   B: W-dir 9-sums of slice t-1 from sIJ[(t+1)&1] -> ws
//   D: reg->LDS write of staged slice -> sIJ[t&1]
//   sync2
// Step loop unrolled by 9 so ring slot (t mod 9) is a static register index.
// ---------------------------------------------------------------------------
__global__ __launch_bounds__(256, 4) void ncc_fused(const float* __restrict__ I,
                                                    const float* __restrict__ J,
                                                    float* __restrict__ bsum) {
  __shared__ float2 sIJ[2][RH][RWP];   // 15744 B (also reused for reduction)
  __shared__ float4 ws4[RH][TWP];      // 12672 B
  __shared__ float  ws1[RH][TWP];      //  3168 B

  const int tid = threadIdx.x;
  const int w0 = blockIdx.x * TW;               // 5
  const int h0 = blockIdx.y * TH;               // 12
  const int c0 = (blockIdx.z % NCHUNK) * DC;    // 8 chunks
  const int batch = blockIdx.z / NCHUNK;        // 2

  const float* Ib = I + (size_t)batch * V_;
  const float* Jb = J + (size_t)batch * V_;

  // A/D stager mapping (tid < 240): 24 rows x 10 float4-quads
  const int sr  = tid / 10;
  const int sq  = tid % 10;
  const int sh  = h0 - 4 + sr;
  const int swq = w0 - 4 + sq * 4;
  const bool s_hv   = (unsigned)sh < (unsigned)H_;
  const bool s_fast = s_hv && (swq >= 0) && (swq + 3 < W_);
  const size_t s_row = (size_t)(s_hv ? sh : 0) * W_;

  // B mapping (tid < 192): 24 rows x 8 runs of 4
  const int br = tid >> 3;
  const int bc = (tid & 7) * 4;

  // C mapping: col tx, output rows hb and hb+1
  const int tx = tid & 31;
  const int hb = (tid >> 5) * 2;

  unsigned ring[5][9];
  float sum0[5], sum1[5];
#pragma unroll
  for (int f = 0; f < 5; ++f) {
    sum0[f] = 0.f; sum1[f] = 0.f;
#pragma unroll
    for (int k = 0; k < 9; ++k) ring[f][k] = 0u;
  }

  float local = 0.f;
  float4 ra = {0,0,0,0}, rb = {0,0,0,0};

#pragma unroll 1
  for (int tb = 0; tb < NSTEP; tb += 9) {
#pragma unroll
    for (int u = 0; u < 9; ++u) {
      const int t = tb + u;
      if (t >= NSTEP) break;

      // ---- A: issue global loads for slice s = c0-4+t ----
      const int s = c0 - 4 + t;
      if (t < DC + 8 && tid < 240) {
        ra = make_float4(0,0,0,0); rb = make_float4(0,0,0,0);
        if (s >= 0 && s < D_ && s_hv) {
          const float* IpRow = Ib + (size_t)s * HW_ + s_row;
          const float* JpRow = Jb + (size_t)s * HW_ + s_row;
          if (s_fast) {
            ra = *(const float4*)(IpRow + swq);
            rb = *(const float4*)(JpRow + swq);
          } else {
            float av[4] = {0,0,0,0}, bv[4] = {0,0,0,0};
#pragma unroll
            for (int e = 0; e < 4; ++e) {
              int w = swq + e;
              if ((unsigned)w < (unsigned)W_) { av[e] = IpRow[w]; bv[e] = JpRow[w]; }
            }
            ra = make_float4(av[0],av[1],av[2],av[3]);
            rb = make_float4(bv[0],bv[1],bv[2],bv[3]);
          }
        }
      }

      // ---- C: H-dir 9-sums of slice t-2 from ws + bf16 D-ring (slot u) ----
      if (t >= 2 && t < DC + 10) {
        float v0 = 0.f, v1 = 0.f, v2 = 0.f, v3 = 0.f, v4 = 0.f;
        float4 k4; float k1v;
#pragma unroll
        for (int k = 0; k < 9; ++k) {
          const float4 a4 = ws4[hb + k][tx];
          const float  a1 = ws1[hb + k][tx];
          if (k == 0) { k4 = a4; k1v = a1; }
          v0 += a4.x; v1 += a4.y; v2 += a4.z; v3 += a4.w; v4 += a1;
        }
        const float4 t4 = ws4[hb + 9][tx];
        const float  t1 = ws1[hb + 9][tx];
        float hv0[5], hv1[5];
        hv0[0] = v0; hv0[1] = v1; hv0[2] = v2; hv0[3] = v3; hv0[4] = v4;
        hv1[0] = v0 + t4.x - k4.x;
        hv1[1] = v1 + t4.y - k4.y;
        hv1[2] = v2 + t4.z - k4.z;
        hv1[3] = v3 + t4.w - k4.w;
        hv1[4] = v4 + t1   - k1v;

#pragma unroll
        for (int f = 0; f < 5; ++f) {
          const float2 old = unpack_bf2(ring[f][u]);
          sum0[f] += hv0[f] - old.x;
          sum1[f] += hv1[f] - old.y;
          ring[f][u] = pack_bf2(hv0[f], hv1[f]);
        }

        if (t >= 10) {
          const float inv = 1.f / 729.f;
          const float cx0 = sum0[4] - sum0[0] * sum0[1] * inv;
          const float iv0 = sum0[2] - sum0[0] * sum0[0] * inv;
          const float jv0 = sum0[3] - sum0[1] * sum0[1] * inv;
          local += cx0 * cx0 * __builtin_amdgcn_rcpf(iv0 * jv0 + 1e-5f);
          const float cx1 = sum1[4] - sum1[0] * sum1[1] * inv;
          const float iv1 = sum1[2] - sum1[0] * sum1[0] * inv;
          const float jv1 = sum1[3] - sum1[1] * sum1[1] * inv;
          local += cx1 * cx1 * __builtin_amdgcn_rcpf(iv1 * jv1 + 1e-5f);
        }
      }

      __syncthreads();

      // ---- B: W-dir 9-sums of slice t-1 from sIJ[(t+1)&1] -> ws ----
      if (t >= 1 && t < DC + 9 && tid < 192) {
        const float2* S = sIJ[(t + 1) & 1][br];
        float4* W4 = ws4[br];
        float*  W1 = ws1[br];
        float2 keep[4];
        float s0 = 0.f, s1 = 0.f, s2 = 0.f, s3 = 0.f, s4 = 0.f;
#pragma unroll
        for (int k = 0; k < 9; ++k) {
          const float2 p = S[bc + k];
          if (k < 4) keep[k] = p;
          s0 += p.x; s1 += p.y; s2 += p.x*p.x; s3 += p.y*p.y; s4 += p.x*p.y;
        }
        W4[bc] = make_float4(s0, s1, s2, s3);
        W1[bc] = s4;
#pragma unroll
        for (int m = 1; m < 4; ++m) {
          const float2 e = S[bc + 8 + m];
          const float2 l = keep[m - 1];
          s0 += e.x - l.x;
          s1 += e.y - l.y;
          s2 += e.x*e.x - l.x*l.x;
          s3 += e.y*e.y - l.y*l.y;
          s4 += e.x*e.y - l.x*l.y;
          W4[bc + m] = make_float4(s0, s1, s2, s3);
          W1[bc + m] = s4;
        }
      }

      // ---- D: write staged regs -> sIJ[t&1] ----
      if (t < DC + 8 && tid < 240) {
        float2* row = sIJ[t & 1][sr];
        row[sq*4+0] = make_float2(ra.x, rb.x);
        row[sq*4+1] = make_float2(ra.y, rb.y);
        row[sq*4+2] = make_float2(ra.z, rb.z);
        row[sq*4+3] = make_float2(ra.w, rb.w);
      }

      __syncthreads();
    }
  }

  // ---- block reduction (reuse sIJ space) -> per-block partial ----
  float* red = (float*)&sIJ[0][0][0];
  red[tid] = local;
  __syncthreads();
  for (int s2 = 128; s2 > 0; s2 >>= 1) {
    if (tid < s2) red[tid] += red[tid + s2];
    __syncthreads();
  }
  if (tid == 0) {
    const int bid = (blockIdx.z * 12 + blockIdx.y) * 5 + blockIdx.x;
    bsum[bid] = red[0];
  }
}

__global__ __launch_bounds__(256) void finalize_k(const float* __restrict__ bsum,
                                                  float* __restrict__ out) {
  __shared__ double red[256];
  double d = 0.0;
  for (int i = threadIdx.x; i < NBLOCKS; i += 256) d += (double)bsum[i];
  red[threadIdx.x] = d;
  __syncthreads();
  for (int s = 128; s > 0; s >>= 1) {
    if (threadIdx.x < s) red[threadIdx.x] += red[threadIdx.x + s];
    __syncthreads();
  }
  if (threadIdx.x == 0) out[0] = (float)(-red[0] / (double)NTOT);
}

extern "C" void kernel_launch(void* const* d_in, const int* in_sizes, int n_in,
                              void* d_out, int out_size, void* d_ws, size_t ws_size,
                              hipStream_t stream) {
  const float* I = (const float*)d_in[0];   // y_true
  const float* J = (const float*)d_in[1];   // y_pred
  float* out = (float*)d_out;
  float* bsum = (float*)d_ws;               // 960 floats

  dim3 grid(W_ / TW, H_ / TH, NCHUNK * 2);  // 5 x 12 x 16 = 960 blocks
  ncc_fused<<<grid, 256, 0, stream>>>(I, J, bsum);
  finalize_k<<<1, 256, 0, stream>>>(bsum, out);
}

// Round 6
// 169.676 us; speedup vs baseline: 1.1570x; 1.1570x over previous
//
#include <hip/hip_runtime.h>

#define D_ 160
#define H_ 192
#define W_ 160
#define HW_ (H_*W_)
#define V_ (D_*H_*W_)
#define NTOT (2*V_)

#define TW 32
#define TH 16
#define DC 20
#define NCHUNK (D_/DC)    // 8
#define RH 24             // TH + 8 halo
#define RWP 41            // 40 cols + 1 pad
#define TWP 33            // 32 cols + 1 pad
#define NSTEP (DC+10)     // 30 real steps; loop padded to 36 (4 x 9)
#define NBLOCKS (5*12*NCHUNK*2)   // 960

// RTNE f32x2 -> packed bf16x2 (p0 high, p1 low) and back.
__device__ inline unsigned pack_bf2(float a, float b) {
  unsigned ua = __float_as_uint(a), ub = __float_as_uint(b);
  ua += 0x7fffu + ((ua >> 16) & 1u);
  ub += 0x7fffu + ((ub >> 16) & 1u);
  return (ua & 0xffff0000u) | (ub >> 16);
}
__device__ inline float2 unpack_bf2(unsigned u) {
  return make_float2(__uint_as_float(u & 0xffff0000u),
                     __uint_as_float(u << 16));
}

// ---------------------------------------------------------------------------
// Fused separable 9x9x9 box filter + NCC.
// Two barriers/step, single ws buffer (31.7 KB LDS -> 5 blocks/CU):
//   A: global->reg loads for slice s=c0-4+t
//   C: H-dir 9-sums of slice t-2 from ws + D-ring (bf16-packed, STATIC slot)
//   sync1
//   B: W-dir 9-sums of slice t-1 from sIJ[(t+1)&1] -> ws
//   D: reg->LDS write of staged slice -> sIJ[t&1]
//   sync2
// Step loop = 4 outer x 9 fully-unrolled inner with NO break (phases
// self-guard on t) so ring[f][u] has static indices -> stays in VGPRs.
// R5 lesson: a break inside the unrolled body demoted ring to scratch
// (WRITE_SIZE 177 MB, +69 MB FETCH, 48 VGPRs).
// ---------------------------------------------------------------------------
__global__ __launch_bounds__(256, 4) void ncc_fused(const float* __restrict__ I,
                                                    const float* __restrict__ J,
                                                    float* __restrict__ bsum) {
  __shared__ float2 sIJ[2][RH][RWP];   // 15744 B (reused for reduction)
  __shared__ float4 ws4[RH][TWP];      // 12672 B
  __shared__ float  ws1[RH][TWP];      //  3168 B

  const int tid = threadIdx.x;
  const int w0 = blockIdx.x * TW;               // 5
  const int h0 = blockIdx.y * TH;               // 12
  const int c0 = (blockIdx.z % NCHUNK) * DC;    // 8 chunks
  const int batch = blockIdx.z / NCHUNK;        // 2

  const float* Ib = I + (size_t)batch * V_;
  const float* Jb = J + (size_t)batch * V_;

  // A/D stager mapping (tid < 240): 24 rows x 10 float4-quads
  const int sr  = tid / 10;
  const int sq  = tid % 10;
  const int sh  = h0 - 4 + sr;
  const int swq = w0 - 4 + sq * 4;
  const bool s_hv   = (unsigned)sh < (unsigned)H_;
  const bool s_fast = s_hv && (swq >= 0) && (swq + 3 < W_);
  const size_t s_row = (size_t)(s_hv ? sh : 0) * W_;

  // B mapping (tid < 192): 24 rows x 8 runs of 4
  const int br = tid >> 3;
  const int bc = (tid & 7) * 4;

  // C mapping: col tx, output rows hb and hb+1
  const int tx = tid & 31;
  const int hb = (tid >> 5) * 2;

  unsigned ring[5][9];
  float sum0[5], sum1[5];
#pragma unroll
  for (int f = 0; f < 5; ++f) {
    sum0[f] = 0.f; sum1[f] = 0.f;
#pragma unroll
    for (int k = 0; k < 9; ++k) ring[f][k] = 0u;
  }

  float local = 0.f;
  float4 ra = {0,0,0,0}, rb = {0,0,0,0};

#pragma unroll 1
  for (int tb = 0; tb < 36; tb += 9) {
#pragma unroll
    for (int u = 0; u < 9; ++u) {
      const int t = tb + u;          // 0..35; phases self-guard (30..35 idle)

      // ---- A: issue global loads for slice s = c0-4+t ----
      const int s = c0 - 4 + t;
      if (t < DC + 8 && tid < 240) {
        ra = make_float4(0,0,0,0); rb = make_float4(0,0,0,0);
        if (s >= 0 && s < D_ && s_hv) {
          const float* IpRow = Ib + (size_t)s * HW_ + s_row;
          const float* JpRow = Jb + (size_t)s * HW_ + s_row;
          if (s_fast) {
            ra = *(const float4*)(IpRow + swq);
            rb = *(const float4*)(JpRow + swq);
          } else {
            float av[4] = {0,0,0,0}, bv[4] = {0,0,0,0};
#pragma unroll
            for (int e = 0; e < 4; ++e) {
              int w = swq + e;
              if ((unsigned)w < (unsigned)W_) { av[e] = IpRow[w]; bv[e] = JpRow[w]; }
            }
            ra = make_float4(av[0],av[1],av[2],av[3]);
            rb = make_float4(bv[0],bv[1],bv[2],bv[3]);
          }
        }
      }

      // ---- C: H-dir 9-sums of slice t-2 from ws + bf16 D-ring (slot u) ----
      if (t >= 2 && t < DC + 10) {
        float v0 = 0.f, v1 = 0.f, v2 = 0.f, v3 = 0.f, v4 = 0.f;
        float4 k4; float k1v;
#pragma unroll
        for (int k = 0; k < 9; ++k) {
          const float4 a4 = ws4[hb + k][tx];
          const float  a1 = ws1[hb + k][tx];
          if (k == 0) { k4 = a4; k1v = a1; }
          v0 += a4.x; v1 += a4.y; v2 += a4.z; v3 += a4.w; v4 += a1;
        }
        const float4 t4 = ws4[hb + 9][tx];
        const float  t1 = ws1[hb + 9][tx];
        float hv0[5], hv1[5];
        hv0[0] = v0; hv0[1] = v1; hv0[2] = v2; hv0[3] = v3; hv0[4] = v4;
        hv1[0] = v0 + t4.x - k4.x;
        hv1[1] = v1 + t4.y - k4.y;
        hv1[2] = v2 + t4.z - k4.z;
        hv1[3] = v3 + t4.w - k4.w;
        hv1[4] = v4 + t1   - k1v;

#pragma unroll
        for (int f = 0; f < 5; ++f) {
          const float2 old = unpack_bf2(ring[f][u]);
          sum0[f] += hv0[f] - old.x;
          sum1[f] += hv1[f] - old.y;
          ring[f][u] = pack_bf2(hv0[f], hv1[f]);
        }

        if (t >= 10) {
          const float inv = 1.f / 729.f;
          const float cx0 = sum0[4] - sum0[0] * sum0[1] * inv;
          const float iv0 = sum0[2] - sum0[0] * sum0[0] * inv;
          const float jv0 = sum0[3] - sum0[1] * sum0[1] * inv;
          local += cx0 * cx0 * __builtin_amdgcn_rcpf(iv0 * jv0 + 1e-5f);
          const float cx1 = sum1[4] - sum1[0] * sum1[1] * inv;
          const float iv1 = sum1[2] - sum1[0] * sum1[0] * inv;
          const float jv1 = sum1[3] - sum1[1] * sum1[1] * inv;
          local += cx1 * cx1 * __builtin_amdgcn_rcpf(iv1 * jv1 + 1e-5f);
        }
      }

      __syncthreads();

      // ---- B: W-dir 9-sums of slice t-1 from sIJ[(t+1)&1] -> ws ----
      if (t >= 1 && t < DC + 9 && tid < 192) {
        const float2* S = sIJ[(t + 1) & 1][br];
        float4* W4 = ws4[br];
        float*  W1 = ws1[br];
        float2 keep[4];
        float s0 = 0.f, s1 = 0.f, s2 = 0.f, s3 = 0.f, s4 = 0.f;
#pragma unroll
        for (int k = 0; k < 9; ++k) {
          const float2 p = S[bc + k];
          if (k < 4) keep[k] = p;
          s0 += p.x; s1 += p.y; s2 += p.x*p.x; s3 += p.y*p.y; s4 += p.x*p.y;
        }
        W4[bc] = make_float4(s0, s1, s2, s3);
        W1[bc] = s4;
#pragma unroll
        for (int m = 1; m < 4; ++m) {
          const float2 e = S[bc + 8 + m];
          const float2 l = keep[m - 1];
          s0 += e.x - l.x;
          s1 += e.y - l.y;
          s2 += e.x*e.x - l.x*l.x;
          s3 += e.y*e.y - l.y*l.y;
          s4 += e.x*e.y - l.x*l.y;
          W4[bc + m] = make_float4(s0, s1, s2, s3);
          W1[bc + m] = s4;
        }
      }

      // ---- D: write staged regs -> sIJ[t&1] ----
      if (t < DC + 8 && tid < 240) {
        float2* row = sIJ[t & 1][sr];
        row[sq*4+0] = make_float2(ra.x, rb.x);
        row[sq*4+1] = make_float2(ra.y, rb.y);
        row[sq*4+2] = make_float2(ra.z, rb.z);
        row[sq*4+3] = make_float2(ra.w, rb.w);
      }

      __syncthreads();
    }
  }

  // ---- block reduction (reuse sIJ space) -> per-block partial ----
  float* red = (float*)&sIJ[0][0][0];
  red[tid] = local;
  __syncthreads();
  for (int s2 = 128; s2 > 0; s2 >>= 1) {
    if (tid < s2) red[tid] += red[tid + s2];
    __syncthreads();
  }
  if (tid == 0) {
    const int bid = (blockIdx.z * 12 + blockIdx.y) * 5 + blockIdx.x;
    bsum[bid] = red[0];
  }
}

__global__ __launch_bounds__(256) void finalize_k(const float* __restrict__ bsum,
                                                  float* __restrict__ out) {
  __shared__ double red[256];
  double d = 0.0;
  for (int i = threadIdx.x; i < NBLOCKS; i += 256) d += (double)bsum[i];
  red[threadIdx.x] = d;
  __syncthreads();
  for (int s = 128; s > 0; s >>= 1) {
    if (threadIdx.x < s) red[threadIdx.x] += red[threadIdx.x + s];
    __syncthreads();
  }
  if (threadIdx.x == 0) out[0] = (float)(-red[0] / (double)NTOT);
}

extern "C" void kernel_launch(void* const* d_in, const int* in_sizes, int n_in,
                              void* d_out, int out_size, void* d_ws, size_t ws_size,
                              hipStream_t stream) {
  const float* I = (const float*)d_in[0];   // y_true
  const float* J = (const float*)d_in[1];   // y_pred
  float* out = (float*)d_out;
  float* bsum = (float*)d_ws;               // 960 floats

  dim3 grid(W_ / TW, H_ / TH, NCHUNK * 2);  // 5 x 12 x 16 = 960 blocks
  ncc_fused<<<grid, 256, 0, stream>>>(I, J, bsum);
  finalize_k<<<1, 256, 0, stream>>>(bsum, out);
}